// Round 1
// baseline (10915.429 us; speedup 1.0000x reference)
//
#include <hip/hip_runtime.h>
#include <hip/hip_fp16.h>

// Stacked-LSTM sequence predictor: B=1024, T=256, IN=2, H1=64 H2=128 H3=256,
// future=16. Batch-parallel persistent kernel: 256 blocks x 512 threads,
// NB=4 batch elems per block, all 271 steps in-kernel. Weights fp16 (transposed,
// k-quad packed) streamed from L2; states fp32 in LDS.

#define NB 4
#define NT 512
#define T_SEQ 256

#define KQ1 17   // K1 = 66 padded to 68
#define KQ2 48   // K2 = 192
#define KQ3 96   // K3 = 384
#define R1 256   // 4*H1
#define R2 512   // 4*H2
#define R3 1024  // 4*H3
#define XS1 72   // [x(2) | h1(64)] padded
#define XS2 200  // [h1(64) | h2(128)] padded
#define XS3 392  // [h2(128) | h3(256)] padded
#define GS 1032

#define N1 (KQ1*R1*4)        // 17408 halfs
#define N2 (N1 + KQ2*R2*4)   // 115712
#define N3 (N2 + KQ3*R3*4)   // 508928

__device__ __forceinline__ float sigm(float x) {
  return __fdividef(1.f, 1.f + __expf(-x));
}
__device__ __forceinline__ float tanh_fast(float x) {
  float t = __expf(-2.f * fabsf(x));
  float r = __fdividef(1.f - t, 1.f + t);
  return copysignf(r, x);
}

// ---------------- weight prep: fp32 [R][K] (split ih/hh) -> fp16 [kq][R][4] ----
__global__ void prep_weights(const float* __restrict__ Wih1, const float* __restrict__ Whh1,
                             const float* __restrict__ Wih2, const float* __restrict__ Whh2,
                             const float* __restrict__ Wih3, const float* __restrict__ Whh3,
                             __half* __restrict__ WT) {
  int idx = blockIdx.x * blockDim.x + threadIdx.x;
  if (idx >= N3) return;
  float v = 0.f;
  if (idx < N1) {
    int e = idx;
    int kq = e >> 10, rem = e & 1023;       // R1*4 = 1024
    int r = rem >> 2, q = rem & 3;
    int k = (kq << 2) + q;
    if (k < 2)       v = Wih1[(r << 1) + k];
    else if (k < 66) v = Whh1[(r << 6) + (k - 2)];
    // k >= 66: zero pad
  } else if (idx < N2) {
    int e = idx - N1;
    int kq = e >> 11, rem = e & 2047;       // R2*4 = 2048
    int r = rem >> 2, q = rem & 3;
    int k = (kq << 2) + q;
    if (k < 64) v = Wih2[(r << 6) + k];
    else        v = Whh2[(r << 7) + (k - 64)];
  } else {
    int e = idx - N2;
    int kq = e >> 12, rem = e & 4095;       // R3*4 = 4096
    int r = rem >> 2, q = rem & 3;
    int k = (kq << 2) + q;
    if (k < 128) v = Wih3[(r << 7) + k];
    else         v = Whh3[(r << 8) + (k - 128)];
  }
  WT[idx] = __float2half(v);
}

// ---------------- gate GEMM: thread owns rows (tid, tid+R/2) x NB batches -----
template <int KQ, int R, int XS>
__device__ __forceinline__ void gate_mm(const __half* __restrict__ WT,
                                        const float* xh,     // LDS [NB][XS]
                                        const float* __restrict__ bih,
                                        const float* __restrict__ bhh,
                                        float* g,            // LDS [NB][GS]
                                        int tid) {
  const int r0 = tid, r1 = tid + (R >> 1);
  float acc0[NB], acc1[NB];
  const float bb0 = bih[r0] + bhh[r0];
  const float bb1 = bih[r1] + bhh[r1];
#pragma unroll
  for (int b = 0; b < NB; ++b) { acc0[b] = bb0; acc1[b] = bb1; }

#pragma unroll 4
  for (int kq = 0; kq < KQ; ++kq) {
    const __half2* wp0 = reinterpret_cast<const __half2*>(WT) + (((kq * R) + r0) << 1);
    const __half2* wp1 = reinterpret_cast<const __half2*>(WT) + (((kq * R) + r1) << 1);
    const __half2 wa0 = wp0[0], wb0 = wp0[1];
    const __half2 wa1 = wp1[0], wb1 = wp1[1];
#pragma unroll
    for (int b = 0; b < NB; ++b) {
      const float4 h = *reinterpret_cast<const float4*>(xh + b * XS + (kq << 2));
      acc0[b] = fmaf(__low2float(wa0),  h.x, acc0[b]);
      acc0[b] = fmaf(__high2float(wa0), h.y, acc0[b]);
      acc0[b] = fmaf(__low2float(wb0),  h.z, acc0[b]);
      acc0[b] = fmaf(__high2float(wb0), h.w, acc0[b]);
      acc1[b] = fmaf(__low2float(wa1),  h.x, acc1[b]);
      acc1[b] = fmaf(__high2float(wa1), h.y, acc1[b]);
      acc1[b] = fmaf(__low2float(wb1),  h.z, acc1[b]);
      acc1[b] = fmaf(__high2float(wb1), h.w, acc1[b]);
    }
  }
#pragma unroll
  for (int b = 0; b < NB; ++b) {
    g[b * GS + r0] = acc0[b];
    g[b * GS + r1] = acc1[b];
  }
}

// ---------------- main persistent kernel --------------------------------------
__global__ __launch_bounds__(NT) void lstm_main(
    const float* __restrict__ input, const int* __restrict__ future_p,
    const float* __restrict__ bih1, const float* __restrict__ bhh1,
    const float* __restrict__ bih2, const float* __restrict__ bhh2,
    const float* __restrict__ bih3, const float* __restrict__ bhh3,
    const float* __restrict__ Wlin, const float* __restrict__ blin,
    const __half* __restrict__ WT,
    float* __restrict__ out) {
  __shared__ __align__(16) float xh1[NB][XS1];
  __shared__ __align__(16) float xh2[NB][XS2];
  __shared__ __align__(16) float xh3[NB][XS3];
  __shared__ float c1s[NB][64];
  __shared__ float c2s[NB][128];
  __shared__ float c3s[NB][256];
  __shared__ float g[NB][GS];
  __shared__ float xnext[NB][2];

  const int tid = threadIdx.x;
  const int b0 = blockIdx.x * NB;
  const __half* WT1 = WT;
  const __half* WT2 = WT + N1;
  const __half* WT3 = WT + N2;

  // zero-init states + pads (pads stay zero forever; padded weights are zero too)
  for (int i = tid; i < NB * XS1; i += NT) (&xh1[0][0])[i] = 0.f;
  for (int i = tid; i < NB * XS2; i += NT) (&xh2[0][0])[i] = 0.f;
  for (int i = tid; i < NB * XS3; i += NT) (&xh3[0][0])[i] = 0.f;
  for (int i = tid; i < NB * 64;  i += NT) (&c1s[0][0])[i] = 0.f;
  for (int i = tid; i < NB * 128; i += NT) (&c2s[0][0])[i] = 0.f;
  for (int i = tid; i < NB * 256; i += NT) (&c3s[0][0])[i] = 0.f;
  __syncthreads();

  const int fut = *future_p;          // 16
  const int nsteps = T_SEQ + fut - 1; // 271

  for (int t = 0; t < nsteps; ++t) {
    // phase 0: feed x into xh1[b][0:2]
    if (tid < NB * 2) {
      const int b = tid >> 1, c = tid & 1;
      const float xv = (t < T_SEQ)
          ? input[((size_t)(b0 + b) * T_SEQ + t) * 2 + c]
          : xnext[b][c];
      xh1[b][c] = xv;
    }
    __syncthreads();

    // ---- layer 1 ----
    if (tid < (R1 >> 1)) gate_mm<KQ1, R1, XS1>(WT1, &xh1[0][0], bih1, bhh1, &g[0][0], tid);
    __syncthreads();
    if (tid < NB * 64) {
      const int b = tid >> 6, j = tid & 63;
      const float gi = g[b][j], gf = g[b][64 + j], gg = g[b][128 + j], go = g[b][192 + j];
      const float c = sigm(gf) * c1s[b][j] + sigm(gi) * tanh_fast(gg);
      const float h = sigm(go) * tanh_fast(c);
      c1s[b][j] = c;
      xh1[b][2 + j] = h;   // for next step's L1
      xh2[b][j] = h;       // input to L2
    }
    __syncthreads();

    // ---- layer 2 ----
    if (tid < (R2 >> 1)) gate_mm<KQ2, R2, XS2>(WT2, &xh2[0][0], bih2, bhh2, &g[0][0], tid);
    __syncthreads();
    if (tid < NB * 128) {
      const int b = tid >> 7, j = tid & 127;
      const float gi = g[b][j], gf = g[b][128 + j], gg = g[b][256 + j], go = g[b][384 + j];
      const float c = sigm(gf) * c2s[b][j] + sigm(gi) * tanh_fast(gg);
      const float h = sigm(go) * tanh_fast(c);
      c2s[b][j] = c;
      xh2[b][64 + j] = h;  // for next step's L2
      xh3[b][j] = h;       // input to L3
    }
    __syncthreads();

    // ---- layer 3 (all 512 threads) ----
    gate_mm<KQ3, R3, XS3>(WT3, &xh3[0][0], bih3, bhh3, &g[0][0], tid);
    __syncthreads();
#pragma unroll
    for (int u = 0; u < 2; ++u) {
      const int job = tid + u * NT;
      const int b = job >> 8, j = job & 255;
      const float gi = g[b][j], gf = g[b][256 + j], gg = g[b][512 + j], go = g[b][768 + j];
      const float c = sigm(gf) * c3s[b][j] + sigm(gi) * tanh_fast(gg);
      const float h = sigm(go) * tanh_fast(c);
      c3s[b][j] = c;
      xh3[b][128 + j] = h; // for next step's L3 (+ final linear)
    }
    __syncthreads();

    // ---- output linear, only when needed (t==255 and future steps) ----
    if (t >= T_SEQ - 1) {
      const int wv = tid >> 6, lane = tid & 63;
      const int b = wv >> 1, ch = wv & 1;  // 8 waves = 4 batch x 2 channels
      float acc = 0.f;
#pragma unroll
      for (int it = 0, k = lane; it < 7; ++it, k += 64) {
        const float xv = (k < 64) ? xh2[b][k] : xh3[b][k - 64]; // [h1|h2|h3]
        acc = fmaf(Wlin[ch * 448 + k], xv, acc);
      }
#pragma unroll
      for (int off = 32; off > 0; off >>= 1) acc += __shfl_down(acc, off, 64);
      if (lane == 0) {
        const float o = acc + blin[ch];
        const int idx = t - (T_SEQ - 1);
        out[((size_t)(b0 + b) * fut + idx) * 2 + ch] = o;
        xnext[b][ch] = o;
      }
      __syncthreads();
    }
  }
}

extern "C" void kernel_launch(void* const* d_in, const int* in_sizes, int n_in,
                              void* d_out, int out_size, void* d_ws, size_t ws_size,
                              hipStream_t stream) {
  const float* input = (const float*)d_in[0];
  const int*   fut   = (const int*)d_in[1];
  const float* Wih1  = (const float*)d_in[2];
  const float* Whh1  = (const float*)d_in[3];
  const float* bih1  = (const float*)d_in[4];
  const float* bhh1  = (const float*)d_in[5];
  const float* Wih2  = (const float*)d_in[6];
  const float* Whh2  = (const float*)d_in[7];
  const float* bih2  = (const float*)d_in[8];
  const float* bhh2  = (const float*)d_in[9];
  const float* Wih3  = (const float*)d_in[10];
  const float* Whh3  = (const float*)d_in[11];
  const float* bih3  = (const float*)d_in[12];
  const float* bhh3  = (const float*)d_in[13];
  const float* Wlin  = (const float*)d_in[14];
  const float* blin  = (const float*)d_in[15];
  float* out = (float*)d_out;

  __half* WT = (__half*)d_ws;  // 508928 halfs ~ 1.02 MB

  prep_weights<<<(N3 + 255) / 256, 256, 0, stream>>>(Wih1, Whh1, Wih2, Whh2, Wih3, Whh3, WT);
  lstm_main<<<256, NT, 0, stream>>>(input, fut,
                                    bih1, bhh1, bih2, bhh2, bih3, bhh3,
                                    Wlin, blin, WT, out);
}

// Round 2
// 8624.290 us; speedup vs baseline: 1.2657x; 1.2657x over previous
//
#include <hip/hip_runtime.h>

// Stacked-LSTM via f16 MFMA. NB=16 batch/block, grid=64, 512 threads (8 waves).
// Weights pre-shuffled to MFMA A-fragment layout (f16); activations f16 in LDS;
// gate accum + c-state in registers (fp32). Per-CU L2 weight stream = 1MB/step.

#define NBATCH 16
#define NT 512
#define T_SEQ 256

#define H1c 64
#define H2c 128
#define H3c 256
#define NJT1 4
#define NJT2 8
#define NJT3 16
#define NKB1 3     // K1 = 66 -> padded 96
#define NKB2 6     // K2 = 192
#define NKB3 12    // K3 = 384
#define KS1 104    // LDS row strides (halfs), chosen so stride/2 mod 32 dwords spreads banks
#define KS2 200
#define KS3 392

#define WSZ1 (NJT1*4*NKB1*512)   // 24576 halfs
#define WSZ2 (NJT2*4*NKB2*512)   // 98304
#define WSZ3 (NJT3*4*NKB3*512)   // 393216
#define WTOT (WSZ1+WSZ2+WSZ3)    // 516096 halfs ~ 1.01 MB

typedef _Float16 half8 __attribute__((ext_vector_type(8)));
typedef _Float16 half4 __attribute__((ext_vector_type(4)));
typedef float f32x4 __attribute__((ext_vector_type(4)));

__device__ __forceinline__ float sigm(float x) {
  return __fdividef(1.f, 1.f + __expf(-x));
}
__device__ __forceinline__ float tanh_fast(float x) {
  float t = __expf(-2.f * fabsf(x));
  float r = __fdividef(1.f - t, 1.f + t);
  return copysignf(r, x);
}

// ---- prep: fp32 [Wih|Whh] -> f16 MFMA A-fragment layout -----------------------
// Block of 512 halfs per (tile, kblock): lane l (0..63) holds 8 halfs:
//   row = tile_row_base + (l&15),  k = kk*32 + (l>>4)*8 + j
// tile tl = q*NJT + jt covers rows q*H + jt*16 .. +15 (q = gate 0..3).
__global__ void prep_weights(const float* __restrict__ Wih1, const float* __restrict__ Whh1,
                             const float* __restrict__ Wih2, const float* __restrict__ Whh2,
                             const float* __restrict__ Wih3, const float* __restrict__ Whh3,
                             _Float16* __restrict__ WT) {
  int idx = blockIdx.x * blockDim.x + threadIdx.x;
  if (idx >= WTOT) return;
  int e, NJT, NKB, H, kin;
  const float *Wih, *Whh;
  if (idx < WSZ1)             { e = idx;             NJT = NJT1; NKB = NKB1; H = H1c; kin = 2;   Wih = Wih1; Whh = Whh1; }
  else if (idx < WSZ1 + WSZ2) { e = idx - WSZ1;      NJT = NJT2; NKB = NKB2; H = H2c; kin = 64;  Wih = Wih2; Whh = Whh2; }
  else                        { e = idx - WSZ1-WSZ2; NJT = NJT3; NKB = NKB3; H = H3c; kin = 128; Wih = Wih3; Whh = Whh3; }
  const int blk = e >> 9, wb = e & 511;
  const int lane = wb >> 3, j = wb & 7;
  const int tl = blk / NKB, kk = blk % NKB;
  const int q = tl / NJT, jt = tl % NJT;
  const int r = q * H + jt * 16 + (lane & 15);
  const int k = kk * 32 + ((lane >> 4) << 3) + j;
  float v = 0.f;
  if (k < kin)          v = Wih[r * kin + k];
  else if (k < kin + H) v = Whh[r * H + (k - kin)];
  WT[idx] = (_Float16)v;
}

// ---- one j-tile of one layer: 4 gate-tiles MFMA + in-register LSTM pointwise --
template <int NJT, int NKB, int KS, int H>
__device__ __forceinline__ void layer_gates(const _Float16* __restrict__ WTl,
                                            const _Float16* xh,   // LDS [NBATCH][KS]
                                            const float* bs,      // LDS [4H] = bih+bhh
                                            int jt, int lane,
                                            float* creg,          // [4] persistent c
                                            half4* hout) {
  const int n  = lane & 15;
  const int l4 = lane >> 4;
  half8 bf[NKB];
#pragma unroll
  for (int kk = 0; kk < NKB; ++kk)
    bf[kk] = *reinterpret_cast<const half8*>(xh + n * KS + kk * 32 + l4 * 8);
  const int j0 = jt * 16 + l4 * 4;
  f32x4 acc[4];
#pragma unroll
  for (int q = 0; q < 4; ++q)
#pragma unroll
    for (int e = 0; e < 4; ++e) acc[q][e] = bs[q * H + j0 + e];
#pragma unroll
  for (int q = 0; q < 4; ++q) {
    const _Float16* wp = WTl + (((size_t)(q * NJT + jt) * NKB) << 9) + (lane << 3);
    half8 a[NKB];
#pragma unroll
    for (int kk = 0; kk < NKB; ++kk)
      a[kk] = *reinterpret_cast<const half8*>(wp + (kk << 9));
#pragma unroll
    for (int kk = 0; kk < NKB; ++kk)
      acc[q] = __builtin_amdgcn_mfma_f32_16x16x32_f16(a[kk], bf[kk], acc[q], 0, 0, 0);
  }
#pragma unroll
  for (int e = 0; e < 4; ++e) {
    const float gi = acc[0][e], gf = acc[1][e], gg = acc[2][e], go = acc[3][e];
    const float cn = sigm(gf) * creg[e] + sigm(gi) * tanh_fast(gg);
    const float h  = sigm(go) * tanh_fast(cn);
    creg[e] = cn;
    (*hout)[e] = (_Float16)h;
  }
}

// ---- main persistent kernel ---------------------------------------------------
__global__ __launch_bounds__(NT, 2) void lstm_main(
    const float* __restrict__ input, const int* __restrict__ future_p,
    const float* __restrict__ bih1, const float* __restrict__ bhh1,
    const float* __restrict__ bih2, const float* __restrict__ bhh2,
    const float* __restrict__ bih3, const float* __restrict__ bhh3,
    const float* __restrict__ Wlin, const float* __restrict__ blin,
    const _Float16* __restrict__ WT,
    float* __restrict__ out) {
  __shared__ _Float16 xh1s[NBATCH][KS1];  // [x(2) | h1(64) | 0-pad]
  __shared__ _Float16 xh2s[NBATCH][KS2];  // [h1(64) | h2(128) | pad]
  __shared__ _Float16 xh3s[NBATCH][KS3];  // [h2(128) | h3(256) | pad]
  __shared__ float bs1[4 * H1c], bs2[4 * H2c], bs3[4 * H3c];
  __shared__ float wlin_s[2][448];

  const int tid = threadIdx.x;
  const int wv = tid >> 6, lane = tid & 63;
  const int n = lane & 15, l4 = lane >> 4;
  const int j0w = l4 * 4;
  const int b0 = blockIdx.x * NBATCH;
  const _Float16* WT1 = WT;
  const _Float16* WT2 = WT + WSZ1;
  const _Float16* WT3 = WT + WSZ1 + WSZ2;

  // init: zero activations (pads must be 0, not poison: 0-weight * NaN = NaN)
  for (int i = tid; i < NBATCH * KS1; i += NT) (&xh1s[0][0])[i] = (_Float16)0.f;
  for (int i = tid; i < NBATCH * KS2; i += NT) (&xh2s[0][0])[i] = (_Float16)0.f;
  for (int i = tid; i < NBATCH * KS3; i += NT) (&xh3s[0][0])[i] = (_Float16)0.f;
  if (tid < 256) bs1[tid] = bih1[tid] + bhh1[tid];
  bs2[tid] = bih2[tid] + bhh2[tid];
  bs3[tid] = bih3[tid] + bhh3[tid];
  bs3[tid + 512] = bih3[tid + 512] + bhh3[tid + 512];
  for (int i = tid; i < 896; i += NT) (&wlin_s[0][0])[i] = Wlin[i];
  if (tid < NBATCH * 2) {  // x(t=0)
    const int nn = tid >> 1, cc = tid & 1;
    xh1s[nn][cc] = (_Float16)input[((size_t)(b0 + nn) * T_SEQ + 0) * 2 + cc];
  }
  __syncthreads();

  const int fut = *future_p;
  const int nsteps = T_SEQ - 1 + fut;  // 271

  float c1r[4] = {0.f, 0.f, 0.f, 0.f};
  float c2r[4] = {0.f, 0.f, 0.f, 0.f};
  float c3ra[4] = {0.f, 0.f, 0.f, 0.f};
  float c3rb[4] = {0.f, 0.f, 0.f, 0.f};
  half4 h1 = {}, h2 = {}, h3a = {}, h3b = {};

  for (int t = 0; t < nsteps; ++t) {
    // P1: L1 (waves 0-3, jt=wv). Reads xh1. Writes h1 -> xh2[j0] (L2 input).
    if (wv < 4) {
      layer_gates<NJT1, NKB1, KS1, H1c>(WT1, &xh1s[0][0], bs1, wv, lane, c1r, &h1);
      *reinterpret_cast<half4*>(&xh2s[n][wv * 16 + j0w]) = h1;
    }
    __syncthreads();

    // P2: L2 (all waves, jt=wv). Reads xh2. Writes h2 -> xh3[j0]; deferred h1 -> xh1.
    layer_gates<NJT2, NKB2, KS2, H2c>(WT2, &xh2s[0][0], bs2, wv, lane, c2r, &h2);
    *reinterpret_cast<half4*>(&xh3s[n][wv * 16 + j0w]) = h2;
    if (wv < 4) {
#pragma unroll
      for (int e = 0; e < 4; ++e) xh1s[n][2 + wv * 16 + j0w + e] = h1[e];
    }
    __syncthreads();

    // P3: L3 (all waves, jt=2wv,2wv+1). Reads xh3. Deferred h2 self-write -> xh2.
    layer_gates<NJT3, NKB3, KS3, H3c>(WT3, &xh3s[0][0], bs3, 2 * wv, lane, c3ra, &h3a);
    layer_gates<NJT3, NKB3, KS3, H3c>(WT3, &xh3s[0][0], bs3, 2 * wv + 1, lane, c3rb, &h3b);
    *reinterpret_cast<half4*>(&xh2s[n][64 + wv * 16 + j0w]) = h2;
    __syncthreads();

    // P4: write h3 -> xh3[128+..]; feed next input x (t+1 < 256).
    *reinterpret_cast<half4*>(&xh3s[n][128 + (2 * wv) * 16 + j0w]) = h3a;
    *reinterpret_cast<half4*>(&xh3s[n][128 + (2 * wv + 1) * 16 + j0w]) = h3b;
    if (t + 1 < T_SEQ && tid < NBATCH * 2) {
      const int nn = tid >> 1, cc = tid & 1;
      xh1s[nn][cc] = (_Float16)input[((size_t)(b0 + nn) * T_SEQ + (t + 1)) * 2 + cc];
    }
    __syncthreads();

    // P5: linear head (t >= 255): out = [h1|h2|h3] @ Wlin^T + blin; feeds next x.
    if (t >= T_SEQ - 1) {
#pragma unroll
      for (int u = 0; u < 4; ++u) {
        const int job = (wv << 2) | u;
        const int bn = job >> 1, ch = job & 1;
        float acc = 0.f;
#pragma unroll
        for (int it = 0; it < 7; ++it) {
          const int k = lane + (it << 6);
          const float xv = (k < 192) ? (float)xh2s[bn][k] : (float)xh3s[bn][k - 64];
          acc = fmaf(wlin_s[ch][k], xv, acc);
        }
#pragma unroll
        for (int off = 32; off > 0; off >>= 1) acc += __shfl_down(acc, off, 64);
        if (lane == 0) {
          const float o = acc + blin[ch];
          out[((size_t)(b0 + bn) * fut + (t - (T_SEQ - 1))) * 2 + ch] = o;
          xh1s[bn][ch] = (_Float16)o;
        }
      }
      __syncthreads();
    }
  }
}

extern "C" void kernel_launch(void* const* d_in, const int* in_sizes, int n_in,
                              void* d_out, int out_size, void* d_ws, size_t ws_size,
                              hipStream_t stream) {
  const float* input = (const float*)d_in[0];
  const int*   fut   = (const int*)d_in[1];
  const float* Wih1  = (const float*)d_in[2];
  const float* Whh1  = (const float*)d_in[3];
  const float* bih1  = (const float*)d_in[4];
  const float* bhh1  = (const float*)d_in[5];
  const float* Wih2  = (const float*)d_in[6];
  const float* Whh2  = (const float*)d_in[7];
  const float* bih2  = (const float*)d_in[8];
  const float* bhh2  = (const float*)d_in[9];
  const float* Wih3  = (const float*)d_in[10];
  const float* Whh3  = (const float*)d_in[11];
  const float* bih3  = (const float*)d_in[12];
  const float* bhh3  = (const float*)d_in[13];
  const float* Wlin  = (const float*)d_in[14];
  const float* blin  = (const float*)d_in[15];
  float* out = (float*)d_out;

  _Float16* WT = (_Float16*)d_ws;  // 516096 halfs ~ 1.01 MB

  prep_weights<<<(WTOT + 255) / 256, 256, 0, stream>>>(Wih1, Whh1, Wih2, Whh2, Wih3, Whh3, WT);
  lstm_main<<<1024 / NBATCH, NT, 0, stream>>>(input, fut,
                                              bih1, bhh1, bih2, bhh2, bih3, bhh3,
                                              Wlin, blin, WT, out);
}

// Round 3
// 5853.262 us; speedup vs baseline: 1.8648x; 1.4734x over previous
//
#include <hip/hip_runtime.h>

// Weight-stationary pipelined stacked-LSTM.
// 16 replicas x 11 blocks (1x L1+LIN, 2x L2-half, 8x L3-slice), 256 thr/block.
// Weights live in VGPRs (MFMA A-fragments, fp16). Activations flow between
// blocks via rings in d_ws with agent-scope release/acquire progress flags.
// Each replica owns 4 groups of 16 batches; groups processed as 2 pairs/step.

#define T_SEQ 256
#define NJT1 4
#define NJT2 8
#define NJT3 16
#define NKB1 3     // K1 = 66 -> padded 96
#define NKB2 6     // K2 = 192
#define NKB3 12    // K3 = 384

#define WSZ1 (NJT1*4*NKB1*512)   // 24576 halfs
#define WSZ2 (NJT2*4*NKB2*512)   // 98304
#define WSZ3 (NJT3*4*NKB3*512)   // 393216
#define WTOT (WSZ1+WSZ2+WSZ3)    // 516096 halfs

typedef _Float16 half8 __attribute__((ext_vector_type(8)));
typedef _Float16 half4 __attribute__((ext_vector_type(4)));
typedef float f32x4 __attribute__((ext_vector_type(4)));

__device__ __forceinline__ float sigm(float x) {
  return __fdividef(1.f, 1.f + __expf(-x));
}
__device__ __forceinline__ float tanh_fast(float x) {
  float t = __expf(-2.f * fabsf(x));
  float r = __fdividef(1.f - t, 1.f + t);
  return copysignf(r, x);
}

__device__ __forceinline__ void wait_ge(int* p, int v) {
  while (__hip_atomic_load(p, __ATOMIC_RELAXED, __HIP_MEMORY_SCOPE_AGENT) < v)
    __builtin_amdgcn_s_sleep(4);
}
__device__ __forceinline__ void acq(int* p) {
  (void)__hip_atomic_load(p, __ATOMIC_ACQUIRE, __HIP_MEMORY_SCOPE_AGENT);
}
__device__ __forceinline__ void rel(int* p, int v) {
  __hip_atomic_store(p, v, __ATOMIC_RELEASE, __HIP_MEMORY_SCOPE_AGENT);
}

// ---- prep: fp32 [Wih|Whh] -> f16 MFMA A-fragment layout (unchanged, verified) --
__global__ void prep_weights(const float* __restrict__ Wih1, const float* __restrict__ Whh1,
                             const float* __restrict__ Wih2, const float* __restrict__ Whh2,
                             const float* __restrict__ Wih3, const float* __restrict__ Whh3,
                             _Float16* __restrict__ WT) {
  int idx = blockIdx.x * blockDim.x + threadIdx.x;
  if (idx >= WTOT) return;
  int e, NJT, NKB, H, kin;
  const float *Wih, *Whh;
  if (idx < WSZ1)             { e = idx;             NJT = NJT1; NKB = NKB1; H = 64;  kin = 2;   Wih = Wih1; Whh = Whh1; }
  else if (idx < WSZ1 + WSZ2) { e = idx - WSZ1;      NJT = NJT2; NKB = NKB2; H = 128; kin = 64;  Wih = Wih2; Whh = Whh2; }
  else                        { e = idx - WSZ1-WSZ2; NJT = NJT3; NKB = NKB3; H = 256; kin = 128; Wih = Wih3; Whh = Whh3; }
  const int blk = e >> 9, wb = e & 511;
  const int lane = wb >> 3, j = wb & 7;
  const int tl = blk / NKB, kk = blk % NKB;
  const int q = tl / NJT, jt = tl % NJT;
  const int r = q * H + jt * 16 + (lane & 15);
  const int k = kk * 32 + ((lane >> 4) << 3) + j;
  float v = 0.f;
  if (k < kin)          v = Wih[r * kin + k];
  else if (k < kin + H) v = Whh[r * H + (k - kin)];
  WT[idx] = (_Float16)v;
}

// ---- main pipelined kernel ----------------------------------------------------
__global__ __launch_bounds__(256, 1) void pipe_main(
    const float* __restrict__ input, const int* __restrict__ future_p,
    const float* __restrict__ bih1, const float* __restrict__ bhh1,
    const float* __restrict__ bih2, const float* __restrict__ bhh2,
    const float* __restrict__ bih3, const float* __restrict__ bhh3,
    const float* __restrict__ Wlin, const float* __restrict__ blin,
    const _Float16* __restrict__ WT,
    _Float16* __restrict__ h1r, _Float16* __restrict__ h2r, _Float16* __restrict__ h3r,
    int* __restrict__ flags, int depth,
    float* __restrict__ out) {
  __shared__ _Float16 xh1[4][16][96];   // role 0 only: [x(2)|h1(64)|pad]
  __shared__ float wlin[2][448];        // role 0 only

  const int fut = *future_p;
  const int nsteps = T_SEQ - 1 + fut;   // 271
  const int dmask = depth - 1;
  const int P = (depth >> 1) < 1 ? 1 : (depth >> 1);
  const int DLT = (depth >> 1) >= 3 ? (depth >> 1) - 2 : 0;

  const int xcd = blockIdx.x & 7, slot = blockIdx.x >> 3;
  const int rep = xcd + 8 * (slot / 11);
  const int role = slot % 11;
  const int rb = rep * 4;               // first group of this replica

  int* pg_h1 = flags;                   // [64]
  int* pg_h2 = flags + 64;              // [64][2]
  int* pg_h3 = flags + 64 + 128;        // [64][8]

  const int tid = threadIdx.x;
  const int w = tid >> 6, lane = tid & 63;
  const int n = lane & 15, l4 = lane >> 4;
  const half8 zero8 = (half8)(_Float16)0.f;

  if (role == 0) {
    // =================== L1 + LIN block ===================
    for (int i = tid; i < 4*16*96; i += 256) (&xh1[0][0][0])[i] = (_Float16)0.f;
    for (int i = tid; i < 896; i += 256) (&wlin[0][0])[i] = Wlin[i];
    half8 a[4][3];
#pragma unroll
    for (int q = 0; q < 4; ++q)
#pragma unroll
      for (int kk = 0; kk < 3; ++kk)
        a[q][kk] = *(const half8*)(WT + ((q*NJT1 + w)*NKB1 + kk)*512 + lane*8);
    float bias[4][4];
#pragma unroll
    for (int q = 0; q < 4; ++q)
#pragma unroll
      for (int e = 0; e < 4; ++e) {
        const int r = q*64 + w*16 + l4*4 + e;
        bias[q][e] = bih1[r] + bhh1[r];
      }
    float c1[4][4] = {};
    __syncthreads();

    for (int it = 0; it <= nsteps; ++it) {
#pragma unroll
      for (int p = 0; p < 2; ++p) {
        const int g0 = rb + 2*p;
        // ---- LIN for tp = it-1 (writes x for step it into xh1) ----
        const int tp = it - 1;
        if (tp >= T_SEQ - 1 && tp < nsteps) {
          if (tid == 0) {
            for (int gg = 0; gg < 2; ++gg) {
              const int g = g0 + gg;
              wait_ge(&pg_h2[g*2+0], tp+1); wait_ge(&pg_h2[g*2+1], tp+1);
              for (int s2 = 0; s2 < 8; ++s2) wait_ge(&pg_h3[g*8+s2], tp+1);
            }
            acq(&pg_h2[g0*2]);
          }
          __syncthreads();
          const int j = tid >> 2, kq = tid & 3;
          const int gg = j >> 5, nn = (j >> 1) & 15, ch = j & 1;
          const int g = g0 + gg;
          const _Float16* h2p = h2r + ((g*depth + (tp & dmask))*16 + nn)*128;
          const _Float16* h3p = h3r + ((g*depth + (tp & dmask))*16 + nn)*256;
          float acc = 0.f;
          for (int k = kq*112; k < kq*112 + 112; ++k) {
            const float xv = (k < 64)  ? (float)xh1[2*p+gg][nn][2+k]
                           : (k < 192) ? (float)h2p[k-64]
                                       : (float)h3p[k-192];
            acc = fmaf(wlin[ch][k], xv, acc);
          }
          acc += __shfl_xor(acc, 1, 64);
          acc += __shfl_xor(acc, 2, 64);
          if ((tid & 3) == 0) {
            const float o = acc + blin[ch];
            out[((size_t)(g*16+nn)*fut + (tp - (T_SEQ-1)))*2 + ch] = o;
            xh1[2*p+gg][nn][ch] = (_Float16)o;   // x for step tp+1 = it
          }
          __syncthreads();
        }
        // ---- L1 for t = it ----
        if (it < nsteps) {
          const int t = it;
          if (t < T_SEQ && tid < 64) {
            const int gg = tid >> 5, nn = (tid >> 1) & 15, ch = tid & 1;
            xh1[2*p+gg][nn][ch] =
                (_Float16)input[((size_t)((g0+gg)*16+nn)*T_SEQ + t)*2 + ch];
          }
          if ((t & (P-1)) == 0 && t > DLT && tid == 0) {  // throttle: h1 ring safety
            for (int gg = 0; gg < 2; ++gg) {
              wait_ge(&pg_h2[(g0+gg)*2+0], t - DLT);
              wait_ge(&pg_h2[(g0+gg)*2+1], t - DLT);
            }
          }
          __syncthreads();
          half8 bf0[3], bf1[3];
#pragma unroll
          for (int kk = 0; kk < 3; ++kk) {
            bf0[kk] = *(const half8*)(&xh1[2*p+0][n][kk*32 + l4*8]);
            bf1[kk] = *(const half8*)(&xh1[2*p+1][n][kk*32 + l4*8]);
          }
          __syncthreads();
#pragma unroll
          for (int gg = 0; gg < 2; ++gg) {
            const int g = g0 + gg;
            f32x4 acc4[4];
#pragma unroll
            for (int q = 0; q < 4; ++q)
#pragma unroll
              for (int e = 0; e < 4; ++e) acc4[q][e] = bias[q][e];
#pragma unroll
            for (int q = 0; q < 4; ++q)
#pragma unroll
              for (int kk = 0; kk < 3; ++kk)
                acc4[q] = __builtin_amdgcn_mfma_f32_16x16x32_f16(
                    a[q][kk], gg ? bf1[kk] : bf0[kk], acc4[q], 0, 0, 0);
            half4 hv;
#pragma unroll
            for (int e = 0; e < 4; ++e) {
              const float cn = sigm(acc4[1][e]) * c1[2*p+gg][e]
                             + sigm(acc4[0][e]) * tanh_fast(acc4[2][e]);
              const float h = sigm(acc4[3][e]) * tanh_fast(cn);
              c1[2*p+gg][e] = cn;
              hv[e] = (_Float16)h;
            }
            *(half4*)(&xh1[2*p+gg][n][2 + w*16 + l4*4]) = hv;
            *(half4*)(h1r + ((g*depth + (t & dmask))*16 + n)*64 + w*16 + l4*4) = hv;
          }
          __syncthreads();
          if (tid < 2) rel(&pg_h1[g0+tid], t+1);
        }
      }
    }
  } else if (role <= 2) {
    // =================== L2 half block ===================
    const int half_ = role - 1;
    const int tile = half_*4 + w;        // 0..7
    half8 a[4][6];
#pragma unroll
    for (int q = 0; q < 4; ++q)
#pragma unroll
      for (int kk = 0; kk < 6; ++kk)
        a[q][kk] = *(const half8*)(WT + WSZ1 + ((q*NJT2 + tile)*NKB2 + kk)*512 + lane*8);
    float bias[4][4];
#pragma unroll
    for (int q = 0; q < 4; ++q)
#pragma unroll
      for (int e = 0; e < 4; ++e) {
        const int r = q*128 + tile*16 + l4*4 + e;
        bias[q][e] = bih2[r] + bhh2[r];
      }
    float c2[4][4] = {};

    for (int t = 0; t < nsteps; ++t) {
#pragma unroll
      for (int p = 0; p < 2; ++p) {
        const int g0 = rb + 2*p;
        if ((t & (P-1)) == 0 && t > DLT) {  // throttle: h2 ring safety vs L3+LIN
          if (tid == 0)
            for (int gg = 0; gg < 2; ++gg)
              for (int s2 = 0; s2 < 8; ++s2)
                wait_ge(&pg_h3[(g0+gg)*8+s2], t - DLT);
          __syncthreads();
        }
        if (lane == 0) {
          wait_ge(&pg_h1[g0], t+1); wait_ge(&pg_h1[g0+1], t+1);
          if (t > 0) {
            wait_ge(&pg_h2[g0*2 + (1-half_)], t);
            wait_ge(&pg_h2[(g0+1)*2 + (1-half_)], t);
          }
          acq(&pg_h1[g0]);
        }
#pragma unroll
        for (int gg = 0; gg < 2; ++gg) {
          const int g = g0 + gg;
          const _Float16* h1p = h1r + ((g*depth + (t & dmask))*16 + n)*64;
          const _Float16* h2p = h2r + ((g*depth + ((t-1) & dmask))*16 + n)*128;
          half8 bf[6];
#pragma unroll
          for (int kk = 0; kk < 2; ++kk) bf[kk] = *(const half8*)(h1p + kk*32 + l4*8);
          if (t > 0) {
#pragma unroll
            for (int kk = 2; kk < 6; ++kk) bf[kk] = *(const half8*)(h2p + (kk-2)*32 + l4*8);
          } else {
#pragma unroll
            for (int kk = 2; kk < 6; ++kk) bf[kk] = zero8;
          }
          f32x4 acc4[4];
#pragma unroll
          for (int q = 0; q < 4; ++q)
#pragma unroll
            for (int e = 0; e < 4; ++e) acc4[q][e] = bias[q][e];
#pragma unroll
          for (int q = 0; q < 4; ++q)
#pragma unroll
            for (int kk = 0; kk < 6; ++kk)
              acc4[q] = __builtin_amdgcn_mfma_f32_16x16x32_f16(a[q][kk], bf[kk], acc4[q], 0, 0, 0);
          half4 hv;
#pragma unroll
          for (int e = 0; e < 4; ++e) {
            const float cn = sigm(acc4[1][e]) * c2[2*p+gg][e]
                           + sigm(acc4[0][e]) * tanh_fast(acc4[2][e]);
            const float h = sigm(acc4[3][e]) * tanh_fast(cn);
            c2[2*p+gg][e] = cn;
            hv[e] = (_Float16)h;
          }
          *(half4*)(h2r + ((g*depth + (t & dmask))*16 + n)*128 + tile*16 + l4*4) = hv;
        }
        __syncthreads();
        if (tid < 2) rel(&pg_h2[(g0+tid)*2 + half_], t+1);
      }
    }
  } else {
    // =================== L3 slice block ===================
    const int slice = role - 3;          // 0..7
    const int tl = slice*2 + (w & 1);    // tile 0..15
    const int s = w >> 1;                // group slot 0..1
    half8 a[4][12];
#pragma unroll
    for (int q = 0; q < 4; ++q)
#pragma unroll
      for (int kk = 0; kk < 12; ++kk)
        a[q][kk] = *(const half8*)(WT + WSZ1 + WSZ2 + ((q*NJT3 + tl)*NKB3 + kk)*512 + lane*8);
    float bias[4][4];
#pragma unroll
    for (int q = 0; q < 4; ++q)
#pragma unroll
      for (int e = 0; e < 4; ++e) {
        const int r = q*256 + tl*16 + l4*4 + e;
        bias[q][e] = bih3[r] + bhh3[r];
      }
    float c3[2][4] = {};

    for (int t = 0; t < nsteps; ++t) {
#pragma unroll
      for (int p = 0; p < 2; ++p) {
        const int g = rb + 2*p + s;
        if (lane == 0) {
          wait_ge(&pg_h2[g*2+0], t+1); wait_ge(&pg_h2[g*2+1], t+1);
          if (t > 0)
            for (int s2 = 0; s2 < 8; ++s2) wait_ge(&pg_h3[g*8+s2], t);
          acq(&pg_h2[g*2]);
        }
        const _Float16* h2p = h2r + ((g*depth + (t & dmask))*16 + n)*128;
        const _Float16* h3p = h3r + ((g*depth + ((t-1) & dmask))*16 + n)*256;
        half8 bf[12];
#pragma unroll
        for (int kk = 0; kk < 4; ++kk) bf[kk] = *(const half8*)(h2p + kk*32 + l4*8);
        if (t > 0) {
#pragma unroll
          for (int kk = 4; kk < 12; ++kk) bf[kk] = *(const half8*)(h3p + (kk-4)*32 + l4*8);
        } else {
#pragma unroll
          for (int kk = 4; kk < 12; ++kk) bf[kk] = zero8;
        }
        f32x4 acc4[4];
#pragma unroll
        for (int q = 0; q < 4; ++q)
#pragma unroll
          for (int e = 0; e < 4; ++e) acc4[q][e] = bias[q][e];
#pragma unroll
        for (int q = 0; q < 4; ++q)
#pragma unroll
          for (int kk = 0; kk < 12; ++kk)
            acc4[q] = __builtin_amdgcn_mfma_f32_16x16x32_f16(a[q][kk], bf[kk], acc4[q], 0, 0, 0);
        half4 hv;
#pragma unroll
        for (int e = 0; e < 4; ++e) {
          const float cn = sigm(acc4[1][e]) * c3[p][e]
                         + sigm(acc4[0][e]) * tanh_fast(acc4[2][e]);
          const float h = sigm(acc4[3][e]) * tanh_fast(cn);
          c3[p][e] = cn;
          hv[e] = (_Float16)h;
        }
        *(half4*)(h3r + ((g*depth + (t & dmask))*16 + n)*256 + tl*16 + l4*4) = hv;
        __syncthreads();
        if (tid < 2) rel(&pg_h3[(rb+2*p+tid)*8 + slice], t+1);
      }
    }
  }
}

extern "C" void kernel_launch(void* const* d_in, const int* in_sizes, int n_in,
                              void* d_out, int out_size, void* d_ws, size_t ws_size,
                              hipStream_t stream) {
  const float* input = (const float*)d_in[0];
  const int*   fut   = (const int*)d_in[1];
  const float* Wih1  = (const float*)d_in[2];
  const float* Whh1  = (const float*)d_in[3];
  const float* bih1  = (const float*)d_in[4];
  const float* bhh1  = (const float*)d_in[5];
  const float* Wih2  = (const float*)d_in[6];
  const float* Whh2  = (const float*)d_in[7];
  const float* bih2  = (const float*)d_in[8];
  const float* bhh2  = (const float*)d_in[9];
  const float* Wih3  = (const float*)d_in[10];
  const float* Whh3  = (const float*)d_in[11];
  const float* bih3  = (const float*)d_in[12];
  const float* bhh3  = (const float*)d_in[13];
  const float* Wlin  = (const float*)d_in[14];
  const float* blin  = (const float*)d_in[15];
  float* out = (float*)d_out;

  _Float16* WT = (_Float16*)d_ws;
  auto need = [](int d) -> size_t {
    return ((size_t)WTOT + (size_t)64 * d * 16 * (64 + 128 + 256)) * 2 + 4096;
  };
  int depth = 16;
  if (ws_size < need(16)) depth = 8;
  if (ws_size < need(8))  depth = 4;

  _Float16* h1r = WT + WTOT;
  _Float16* h2r = h1r + (size_t)64 * depth * 16 * 64;
  _Float16* h3r = h2r + (size_t)64 * depth * 16 * 128;
  int* flags = (int*)(h3r + (size_t)64 * depth * 16 * 256);

  prep_weights<<<(WTOT + 255) / 256, 256, 0, stream>>>(Wih1, Whh1, Wih2, Whh2, Wih3, Whh3, WT);
  hipMemsetAsync(flags, 0, 4096, stream);
  pipe_main<<<176, 256, 0, stream>>>(input, fut,
                                     bih1, bhh1, bih2, bhh2, bih3, bhh3,
                                     Wlin, blin, WT, h1r, h2r, h3r, flags, depth, out);
}

// Round 4
// 2999.761 us; speedup vs baseline: 3.6388x; 1.9512x over previous
//
#include <hip/hip_runtime.h>

// Weight-stationary pipelined stacked-LSTM, v4: fence-free MALL handoffs.
// 16 replicas x 11 blocks (1x L1+LIN, 2x L2-half, 8x L3-slice), 256 thr/block.
// Weights in VGPRs (MFMA A-fragments, fp16). Ring data + flags move via
// RELAXED system-scope atomics (sc0 sc1 -> MALL), no wbl2/inv fences.
// One wait + one flag release per block per step (all 4 groups merged).

#define T_SEQ 256
#define NJT1 4
#define NJT2 8
#define NJT3 16
#define NKB1 3     // K1 = 66 -> padded 96   [h1(64) | x(2) | pad]
#define NKB2 6     // K2 = 192               [h1(64) | h2(128)]
#define NKB3 12    // K3 = 384               [h2(128) | h3(256)]

#define WSZ1 (NJT1*4*NKB1*512)   // 24576 halfs
#define WSZ2 (NJT2*4*NKB2*512)   // 98304
#define WSZ3 (NJT3*4*NKB3*512)   // 393216
#define WTOT (WSZ1+WSZ2+WSZ3)    // 516096 halfs ~ 1.01 MB

typedef _Float16 half8 __attribute__((ext_vector_type(8)));
typedef _Float16 half4 __attribute__((ext_vector_type(4)));
typedef float f32x4 __attribute__((ext_vector_type(4)));

union H4u { unsigned long long u; half4 h; };
union H8u { unsigned long long u[2]; half8 h; };

__device__ __forceinline__ float sigm(float x) {
  return __fdividef(1.f, 1.f + __expf(-x));
}
__device__ __forceinline__ float tanh_fast(float x) {
  float t = __expf(-2.f * fabsf(x));
  float r = __fdividef(1.f - t, 1.f + t);
  return copysignf(r, x);
}

// --- MALL-coherent primitives (relaxed system scope: sc0 sc1, no fences) ---
__device__ __forceinline__ unsigned long long ld64(const _Float16* p) {
  return __hip_atomic_load((const unsigned long long*)p, __ATOMIC_RELAXED,
                           __HIP_MEMORY_SCOPE_SYSTEM);
}
__device__ __forceinline__ half8 ldh8(const _Float16* p) {
  H8u r; r.u[0] = ld64(p); r.u[1] = ld64(p + 4);
  return r.h;
}
__device__ __forceinline__ void st64(_Float16* p, half4 v) {
  H4u r; r.h = v;
  __hip_atomic_store((unsigned long long*)p, r.u, __ATOMIC_RELAXED,
                     __HIP_MEMORY_SCOPE_SYSTEM);
}
__device__ __forceinline__ void stflag(int* p, int v) {
  __hip_atomic_store(p, v, __ATOMIC_RELAXED, __HIP_MEMORY_SCOPE_SYSTEM);
}
// lane-parallel multi-flag wait: each lane checks its (p, tg); tg=INT_MIN -> pass
__device__ __forceinline__ void multi_wait(int* p, int tg) {
  while (true) {
    const int v = __hip_atomic_load(p, __ATOMIC_RELAXED, __HIP_MEMORY_SCOPE_SYSTEM);
    if (__all(v >= tg)) break;
    __builtin_amdgcn_s_sleep(2);
  }
  asm volatile("" ::: "memory");
}

// ---- prep: fp32 weights -> f16 MFMA A-fragment layout -------------------------
// lane l holds 8 halfs: row = tilebase + (l&15), k = kk*32 + (l>>4)*8 + j.
__global__ void prep_weights(const float* __restrict__ Wih1, const float* __restrict__ Whh1,
                             const float* __restrict__ Wih2, const float* __restrict__ Whh2,
                             const float* __restrict__ Wih3, const float* __restrict__ Whh3,
                             _Float16* __restrict__ WT) {
  int idx = blockIdx.x * blockDim.x + threadIdx.x;
  if (idx >= WTOT) return;
  float v = 0.f;
  if (idx < WSZ1) {
    const int e = idx, blk = e >> 9, wb = e & 511;
    const int lane = wb >> 3, j = wb & 7;
    const int tl = blk / NKB1, kk = blk % NKB1;
    const int q = tl / NJT1, jt = tl % NJT1;
    const int r = q * 64 + jt * 16 + (lane & 15);
    const int k = kk * 32 + ((lane >> 4) << 3) + j;
    if (k < 64)       v = Whh1[r * 64 + k];          // h1 at k 0..63
    else if (k < 66)  v = Wih1[r * 2 + (k - 64)];    // x at k 64,65
  } else if (idx < WSZ1 + WSZ2) {
    const int e = idx - WSZ1, blk = e >> 9, wb = e & 511;
    const int lane = wb >> 3, j = wb & 7;
    const int tl = blk / NKB2, kk = blk % NKB2;
    const int q = tl / NJT2, jt = tl % NJT2;
    const int r = q * 128 + jt * 16 + (lane & 15);
    const int k = kk * 32 + ((lane >> 4) << 3) + j;
    if (k < 64)       v = Wih2[r * 64 + k];          // h1
    else              v = Whh2[r * 128 + (k - 64)];  // h2
  } else {
    const int e = idx - WSZ1 - WSZ2, blk = e >> 9, wb = e & 511;
    const int lane = wb >> 3, j = wb & 7;
    const int tl = blk / NKB3, kk = blk % NKB3;
    const int q = tl / NJT3, jt = tl % NJT3;
    const int r = q * 256 + jt * 16 + (lane & 15);
    const int k = kk * 32 + ((lane >> 4) << 3) + j;
    if (k < 128)      v = Wih3[r * 128 + k];          // h2
    else              v = Whh3[r * 256 + (k - 128)];  // h3
  }
  WT[idx] = (_Float16)v;
}

// ---- main pipelined kernel ----------------------------------------------------
__global__ __launch_bounds__(256, 1) void pipe_main(
    const float* __restrict__ input, const int* __restrict__ future_p,
    const float* __restrict__ bih1, const float* __restrict__ bhh1,
    const float* __restrict__ bih2, const float* __restrict__ bhh2,
    const float* __restrict__ bih3, const float* __restrict__ bhh3,
    const float* __restrict__ Wlin, const float* __restrict__ blin,
    const _Float16* __restrict__ WT,
    _Float16* __restrict__ h1r, _Float16* __restrict__ h2r, _Float16* __restrict__ h3r,
    int* __restrict__ flags, int depth,
    float* __restrict__ out) {
  __shared__ __align__(16) _Float16 xh1[4][16][96];  // role 0: [h1(64)|x(2)|pad]
  __shared__ float wlin[2][448];                     // role 0

  const int fut = *future_p;
  const int nsteps = T_SEQ - 1 + fut;   // 271
  const int dmask = depth - 1;

  const int xcd = blockIdx.x & 7, slot = blockIdx.x >> 3;
  const int rep = xcd + 8 * (slot / 11);
  const int role = slot % 11;
  const int rb = rep * 4;               // first group of this replica

  int* fl1 = flags;                     // [16]
  int* fl2 = flags + 16;                // [16][2]
  int* fl3 = flags + 48;                // [16][8]

  const int tid = threadIdx.x;
  const int w = tid >> 6, lane = tid & 63;
  const int n = lane & 15, l4 = lane >> 4;
  const int NEG = (int)0x80000000;

  if (role == 0) {
    // =================== L1 + LIN block ===================
    for (int i = tid; i < 4*16*96; i += 256) (&xh1[0][0][0])[i] = (_Float16)0.f;
    for (int i = tid; i < 896; i += 256) (&wlin[0][0])[i] = Wlin[i];
    half8 a[4][3];
#pragma unroll
    for (int q = 0; q < 4; ++q)
#pragma unroll
      for (int kk = 0; kk < 3; ++kk)
        a[q][kk] = *(const half8*)(WT + ((q*NJT1 + w)*NKB1 + kk)*512 + lane*8);
    float bias[4][4];
#pragma unroll
    for (int q = 0; q < 4; ++q)
#pragma unroll
      for (int e = 0; e < 4; ++e) {
        const int r = q*64 + w*16 + l4*4 + e;
        bias[q][e] = bih1[r] + bhh1[r];
      }
    float c1[4][4] = {};
    __syncthreads();

    for (int it = 0; it <= nsteps; ++it) {
      const int tp = it - 1;
      // ---- phase A: LIN for tp (writes x for step it); input feed for it ----
      if (tp >= T_SEQ - 1 && tp < nsteps) {
        { int* wp; int wtg;
          if (lane < 2)       { wp = fl2 + rep*2 + lane;   wtg = tp + 1; }
          else if (lane < 10) { wp = fl3 + rep*8 + lane-2; wtg = tp + 1; }
          else                { wp = fl1;                  wtg = NEG; }
          multi_wait(wp, wtg);
        }
        const int kq = tid & 1, ch = (tid >> 1) & 1, nn = (tid >> 2) & 15, gl = tid >> 6;
        const int g = rb + gl;
        const int tdp = tp & dmask;
        const _Float16* h2p = h2r + ((size_t)(g*depth + tdp)*16 + nn)*128;
        const _Float16* h3p = h3r + ((size_t)(g*depth + tdp)*16 + nn)*256;
        float acc = 0.f;
        for (int k = kq*224; k < kq*224 + 224; k += 4) {
          half4 xv;
          if (k < 64)        xv = *(const half4*)(&xh1[gl][nn][k]);
          else if (k < 192)  { H4u u; u.u = ld64(h2p + (k - 64));  xv = u.h; }
          else               { H4u u; u.u = ld64(h3p + (k - 192)); xv = u.h; }
          const float* wl = &wlin[ch][k];
          acc = fmaf(wl[0], (float)xv[0], acc);
          acc = fmaf(wl[1], (float)xv[1], acc);
          acc = fmaf(wl[2], (float)xv[2], acc);
          acc = fmaf(wl[3], (float)xv[3], acc);
        }
        acc += __shfl_xor(acc, 1, 64);
        if (kq == 0) {
          const float o = acc + blin[ch];
          out[((size_t)(g*16 + nn)*fut + (tp - (T_SEQ - 1)))*2 + ch] = o;
          xh1[gl][nn][64 + ch] = (_Float16)o;
        }
      }
      if (it < T_SEQ && tid < 128) {
        const int gl = tid >> 5, nn = (tid >> 1) & 15, ch = tid & 1;
        xh1[gl][nn][64 + ch] =
            (_Float16)input[((size_t)((rb+gl)*16 + nn)*T_SEQ + it)*2 + ch];
      }
      __syncthreads();

      // ---- phase B/C: L1 step it ----
      if (it < nsteps) {
        const int t = it;
        { int* wp; int wtg;   // h1-ring backpressure
          if (lane < 2) { wp = fl2 + rep*2 + lane; wtg = t - dmask; }
          else          { wp = fl1;                wtg = NEG; }
          multi_wait(wp, wtg);
        }
        half8 bf[4][3];
#pragma unroll
        for (int gl = 0; gl < 4; ++gl)
#pragma unroll
          for (int kk = 0; kk < 3; ++kk)
            bf[gl][kk] = *(const half8*)(&xh1[gl][n][kk*32 + l4*8]);
        __syncthreads();
        const int td = t & dmask;
#pragma unroll
        for (int gl = 0; gl < 4; ++gl) {
          f32x4 acc4[4];
#pragma unroll
          for (int q = 0; q < 4; ++q)
#pragma unroll
            for (int e = 0; e < 4; ++e) acc4[q][e] = bias[q][e];
#pragma unroll
          for (int q = 0; q < 4; ++q)
#pragma unroll
            for (int kk = 0; kk < 3; ++kk)
              acc4[q] = __builtin_amdgcn_mfma_f32_16x16x32_f16(a[q][kk], bf[gl][kk], acc4[q], 0, 0, 0);
          half4 hv;
#pragma unroll
          for (int e = 0; e < 4; ++e) {
            const float cn = sigm(acc4[1][e]) * c1[gl][e]
                           + sigm(acc4[0][e]) * tanh_fast(acc4[2][e]);
            const float h = sigm(acc4[3][e]) * tanh_fast(cn);
            c1[gl][e] = cn;
            hv[e] = (_Float16)h;
          }
          *(half4*)(&xh1[gl][n][w*16 + l4*4]) = hv;
          st64(h1r + ((size_t)((rb+gl)*depth + td)*16 + n)*64 + w*16 + l4*4, hv);
        }
        asm volatile("s_waitcnt vmcnt(0)" ::: "memory");
        __syncthreads();
        if (tid == 0) stflag(fl1 + rep, t + 1);
      }
    }
  } else if (role <= 2) {
    // =================== L2 half block ===================
    const int half_ = role - 1;
    const int tile = half_*4 + w;        // 0..7
    half8 a[4][6];
#pragma unroll
    for (int q = 0; q < 4; ++q)
#pragma unroll
      for (int kk = 0; kk < 6; ++kk)
        a[q][kk] = *(const half8*)(WT + WSZ1 + ((q*NJT2 + tile)*NKB2 + kk)*512 + lane*8);
    float bias[4][4];
#pragma unroll
    for (int q = 0; q < 4; ++q)
#pragma unroll
      for (int e = 0; e < 4; ++e) {
        const int r = q*128 + tile*16 + l4*4 + e;
        bias[q][e] = bih2[r] + bhh2[r];
      }
    float c2[4][4] = {};

    for (int t = 0; t < nsteps; ++t) {
      { int* wp; int wtg;
        if (lane == 0)      { wp = fl1 + rep;                 wtg = t + 1; }
        else if (lane == 1) { wp = fl2 + rep*2 + (1 - half_); wtg = t; }
        else if (lane < 10) { wp = fl3 + rep*8 + lane - 2;    wtg = t - dmask; }
        else                { wp = fl1;                       wtg = NEG; }
        multi_wait(wp, wtg);
      }
      const int td = t & dmask, td1 = (t - 1) & dmask;
      half8 bf[4][6];
#pragma unroll
      for (int gl = 0; gl < 4; ++gl) {
        const int g = rb + gl;
        const _Float16* h1p = h1r + ((size_t)(g*depth + td)*16 + n)*64;
        bf[gl][0] = ldh8(h1p + l4*8);
        bf[gl][1] = ldh8(h1p + 32 + l4*8);
        if (t > 0) {
          const _Float16* h2p = h2r + ((size_t)(g*depth + td1)*16 + n)*128;
#pragma unroll
          for (int kk = 2; kk < 6; ++kk) bf[gl][kk] = ldh8(h2p + (kk-2)*32 + l4*8);
        } else {
#pragma unroll
          for (int kk = 2; kk < 6; ++kk) bf[gl][kk] = half8{};
        }
      }
#pragma unroll
      for (int gl = 0; gl < 4; ++gl) {
        f32x4 acc4[4];
#pragma unroll
        for (int q = 0; q < 4; ++q)
#pragma unroll
          for (int e = 0; e < 4; ++e) acc4[q][e] = bias[q][e];
#pragma unroll
        for (int q = 0; q < 4; ++q)
#pragma unroll
          for (int kk = 0; kk < 6; ++kk)
            acc4[q] = __builtin_amdgcn_mfma_f32_16x16x32_f16(a[q][kk], bf[gl][kk], acc4[q], 0, 0, 0);
        half4 hv;
#pragma unroll
        for (int e = 0; e < 4; ++e) {
          const float cn = sigm(acc4[1][e]) * c2[gl][e]
                         + sigm(acc4[0][e]) * tanh_fast(acc4[2][e]);
          const float h = sigm(acc4[3][e]) * tanh_fast(cn);
          c2[gl][e] = cn;
          hv[e] = (_Float16)h;
        }
        st64(h2r + ((size_t)((rb+gl)*depth + td)*16 + n)*128 + tile*16 + l4*4, hv);
      }
      asm volatile("s_waitcnt vmcnt(0)" ::: "memory");
      __syncthreads();
      if (tid == 0) stflag(fl2 + rep*2 + half_, t + 1);
    }
  } else {
    // =================== L3 slice block ===================
    const int slice = role - 3;          // 0..7
    const int tl = slice*2 + (w & 1);    // tile 0..15
    const int gp = w >> 1;               // group-pair 0..1
    half8 a[4][12];
#pragma unroll
    for (int q = 0; q < 4; ++q)
#pragma unroll
      for (int kk = 0; kk < 12; ++kk)
        a[q][kk] = *(const half8*)(WT + WSZ1 + WSZ2 + ((q*NJT3 + tl)*NKB3 + kk)*512 + lane*8);
    float bias[4][4];
#pragma unroll
    for (int q = 0; q < 4; ++q)
#pragma unroll
      for (int e = 0; e < 4; ++e) {
        const int r = q*256 + tl*16 + l4*4 + e;
        bias[q][e] = bih3[r] + bhh3[r];
      }
    float c3[2][4] = {};

    for (int t = 0; t < nsteps; ++t) {
      { int* wp; int wtg;
        if (lane < 2)       { wp = fl2 + rep*2 + lane;     wtg = t + 1; }
        else if (lane < 10) { wp = fl3 + rep*8 + lane - 2; wtg = t; }
        else                { wp = fl1;                    wtg = NEG; }
        multi_wait(wp, wtg);
      }
      const int td = t & dmask, td1 = (t - 1) & dmask;
      half8 bf[2][12];
#pragma unroll
      for (int j = 0; j < 2; ++j) {
        const int g = rb + gp*2 + j;
        const _Float16* h2p = h2r + ((size_t)(g*depth + td)*16 + n)*128;
#pragma unroll
        for (int kk = 0; kk < 4; ++kk) bf[j][kk] = ldh8(h2p + kk*32 + l4*8);
        if (t > 0) {
          const _Float16* h3p = h3r + ((size_t)(g*depth + td1)*16 + n)*256;
#pragma unroll
          for (int kk = 4; kk < 12; ++kk) bf[j][kk] = ldh8(h3p + (kk-4)*32 + l4*8);
        } else {
#pragma unroll
          for (int kk = 4; kk < 12; ++kk) bf[j][kk] = half8{};
        }
      }
#pragma unroll
      for (int j = 0; j < 2; ++j) {
        const int g = rb + gp*2 + j;
        f32x4 acc4[4];
#pragma unroll
        for (int q = 0; q < 4; ++q)
#pragma unroll
          for (int e = 0; e < 4; ++e) acc4[q][e] = bias[q][e];
#pragma unroll
        for (int q = 0; q < 4; ++q)
#pragma unroll
          for (int kk = 0; kk < 12; ++kk)
            acc4[q] = __builtin_amdgcn_mfma_f32_16x16x32_f16(a[q][kk], bf[j][kk], acc4[q], 0, 0, 0);
        half4 hv;
#pragma unroll
        for (int e = 0; e < 4; ++e) {
          const float cn = sigm(acc4[1][e]) * c3[j][e]
                         + sigm(acc4[0][e]) * tanh_fast(acc4[2][e]);
          const float h = sigm(acc4[3][e]) * tanh_fast(cn);
          c3[j][e] = cn;
          hv[e] = (_Float16)h;
        }
        st64(h3r + ((size_t)(g*depth + td)*16 + n)*256 + tl*16 + l4*4, hv);
      }
      asm volatile("s_waitcnt vmcnt(0)" ::: "memory");
      __syncthreads();
      if (tid == 0) stflag(fl3 + rep*8 + slice, t + 1);
    }
  }
}

extern "C" void kernel_launch(void* const* d_in, const int* in_sizes, int n_in,
                              void* d_out, int out_size, void* d_ws, size_t ws_size,
                              hipStream_t stream) {
  const float* input = (const float*)d_in[0];
  const int*   fut   = (const int*)d_in[1];
  const float* Wih1  = (const float*)d_in[2];
  const float* Whh1  = (const float*)d_in[3];
  const float* bih1  = (const float*)d_in[4];
  const float* bhh1  = (const float*)d_in[5];
  const float* Wih2  = (const float*)d_in[6];
  const float* Whh2  = (const float*)d_in[7];
  const float* bih2  = (const float*)d_in[8];
  const float* bhh2  = (const float*)d_in[9];
  const float* Wih3  = (const float*)d_in[10];
  const float* Whh3  = (const float*)d_in[11];
  const float* bih3  = (const float*)d_in[12];
  const float* bhh3  = (const float*)d_in[13];
  const float* Wlin  = (const float*)d_in[14];
  const float* blin  = (const float*)d_in[15];
  float* out = (float*)d_out;

  _Float16* WT = (_Float16*)d_ws;
  auto need = [](int d) -> size_t {
    return ((size_t)WTOT + (size_t)64 * d * 16 * (64 + 128 + 256)) * 2 + 4096;
  };
  int depth = 8;
  if (ws_size < need(8)) depth = 4;

  _Float16* h1r = WT + WTOT;
  _Float16* h2r = h1r + (size_t)64 * depth * 16 * 64;
  _Float16* h3r = h2r + (size_t)64 * depth * 16 * 128;
  int* flags = (int*)(h3r + (size_t)64 * depth * 16 * 256);

  prep_weights<<<(WTOT + 255) / 256, 256, 0, stream>>>(Wih1, Whh1, Wih2, Whh2, Wih3, Whh3, WT);
  hipMemsetAsync(flags, 0, 4096, stream);
  pipe_main<<<176, 256, 0, stream>>>(input, fut,
                                     bih1, bhh1, bih2, bhh2, bih3, bhh3,
                                     Wlin, blin, WT, h1r, h2r, h3r, flags, depth, out);
}

// Round 5
// 2266.780 us; speedup vs baseline: 4.8154x; 1.3234x over previous
//
#include <hip/hip_runtime.h>

// Weight-stationary pipelined stacked-LSTM, v5.
// 32 replicas x 5 blocks: role 0 = L1+L2+LIN fused (recurrences LDS-local),
// roles 1-4 = L3 quarter-slices. Only cross-block recurrent cycle: h3<->h3,
// one MALL hop/step. Lane-predicated polls, 256B-padded flags.

#define T_SEQ 256
#define NREP 32
#define DEPTH 8
#define DMASK 7

#define NJT1 4
#define NJT2 8
#define NJT3 16
#define NKB1 3     // K1 = 66 -> padded 96  [h1(64) | x(2) | pad]
#define NKB2 6     // K2 = 192              [h1(64) | h2(128)]
#define NKB3 12    // K3 = 384              [h2(128) | h3(256)]

#define WSZ1 (NJT1*4*NKB1*512)   // 24576 halfs
#define WSZ2 (NJT2*8*NKB2*256)   // placeholder (unused math guard)
#undef WSZ2
#define WSZ2 (NJT2*4*NKB2*512)   // 98304
#define WSZ3 (NJT3*4*NKB3*512)   // 393216
#define WTOT (WSZ1+WSZ2+WSZ3)    // 516096 halfs ~ 1.01 MB

// ring strides in halfs
#define H2_G    (16*128)
#define H2_SLOT (2*H2_G)
#define H2_REP  (DEPTH*H2_SLOT)
#define H3_G    (16*256)
#define H3_SLOT (2*H3_G)
#define H3_REP  (DEPTH*H3_SLOT)

typedef _Float16 half8 __attribute__((ext_vector_type(8)));
typedef _Float16 half4 __attribute__((ext_vector_type(4)));
typedef float f32x4 __attribute__((ext_vector_type(4)));

union H4u { unsigned long long u; half4 h; };
union H8u { unsigned long long u[2]; half8 h; };

__device__ __forceinline__ float sigm(float x) {
  return __fdividef(1.f, 1.f + __expf(-x));
}
__device__ __forceinline__ float tanh_fast(float x) {
  float t = __expf(-2.f * fabsf(x));
  float r = __fdividef(1.f - t, 1.f + t);
  return copysignf(r, x);
}

// --- MALL-coherent primitives (relaxed system scope, no fences) ---
__device__ __forceinline__ unsigned long long ld64(const _Float16* p) {
  return __hip_atomic_load((const unsigned long long*)p, __ATOMIC_RELAXED,
                           __HIP_MEMORY_SCOPE_SYSTEM);
}
__device__ __forceinline__ half8 ldh8(const _Float16* p) {
  H8u r; r.u[0] = ld64(p); r.u[1] = ld64(p + 4);
  return r.h;
}
__device__ __forceinline__ void st64(_Float16* p, half4 v) {
  H4u r; r.h = v;
  __hip_atomic_store((unsigned long long*)p, r.u, __ATOMIC_RELAXED,
                     __HIP_MEMORY_SCOPE_SYSTEM);
}
__device__ __forceinline__ void stflag(int* p, int v) {
  __hip_atomic_store(p, v, __ATOMIC_RELAXED, __HIP_MEMORY_SCOPE_SYSTEM);
}
// lanes 0-3 poll fl3[0..3] >= t3; lane 4 polls flf >= tf (skipped if tf==INT_MIN).
// All other lanes idle (no load -> no MALL traffic).
__device__ __forceinline__ void wait_rep(int* fb, int t3, int tf) {
  const int lane = threadIdx.x & 63;
  const bool act = (lane < 4) || ((lane == 4) && (tf != (int)0x80000000));
  int* p = fb + (lane < 5 ? lane : 0) * 64;
  const int tg = (lane < 4) ? t3 : tf;
  while (true) {
    int v = 0x7fffffff;
    if (act) v = __hip_atomic_load(p, __ATOMIC_RELAXED, __HIP_MEMORY_SCOPE_SYSTEM);
    if (__all(v >= tg)) break;
    __builtin_amdgcn_s_sleep(1);
  }
  asm volatile("" ::: "memory");
}

// ---- prep: fp32 weights -> f16 MFMA A-fragment layout (verified R4) -----------
__global__ void prep_weights(const float* __restrict__ Wih1, const float* __restrict__ Whh1,
                             const float* __restrict__ Wih2, const float* __restrict__ Whh2,
                             const float* __restrict__ Wih3, const float* __restrict__ Whh3,
                             _Float16* __restrict__ WT) {
  int idx = blockIdx.x * blockDim.x + threadIdx.x;
  if (idx >= WTOT) return;
  float v = 0.f;
  if (idx < WSZ1) {
    const int e = idx, blk = e >> 9, wb = e & 511;
    const int lane = wb >> 3, j = wb & 7;
    const int tl = blk / NKB1, kk = blk % NKB1;
    const int q = tl / NJT1, jt = tl % NJT1;
    const int r = q * 64 + jt * 16 + (lane & 15);
    const int k = kk * 32 + ((lane >> 4) << 3) + j;
    if (k < 64)       v = Whh1[r * 64 + k];
    else if (k < 66)  v = Wih1[r * 2 + (k - 64)];
  } else if (idx < WSZ1 + WSZ2) {
    const int e = idx - WSZ1, blk = e >> 9, wb = e & 511;
    const int lane = wb >> 3, j = wb & 7;
    const int tl = blk / NKB2, kk = blk % NKB2;
    const int q = tl / NJT2, jt = tl % NJT2;
    const int r = q * 128 + jt * 16 + (lane & 15);
    const int k = kk * 32 + ((lane >> 4) << 3) + j;
    if (k < 64)       v = Wih2[r * 64 + k];
    else              v = Whh2[r * 128 + (k - 64)];
  } else {
    const int e = idx - WSZ1 - WSZ2, blk = e >> 9, wb = e & 511;
    const int lane = wb >> 3, j = wb & 7;
    const int tl = blk / NKB3, kk = blk % NKB3;
    const int q = tl / NJT3, jt = tl % NJT3;
    const int r = q * 256 + jt * 16 + (lane & 15);
    const int k = kk * 32 + ((lane >> 4) << 3) + j;
    if (k < 128)      v = Wih3[r * 128 + k];
    else              v = Whh3[r * 256 + (k - 128)];
  }
  WT[idx] = (_Float16)v;
}

// ---- main pipelined kernel ----------------------------------------------------
__global__ __launch_bounds__(256, 1) void pipe_main(
    const float* __restrict__ input, const int* __restrict__ future_p,
    const float* __restrict__ bih1, const float* __restrict__ bhh1,
    const float* __restrict__ bih2, const float* __restrict__ bhh2,
    const float* __restrict__ bih3, const float* __restrict__ bhh3,
    const float* __restrict__ Wlin, const float* __restrict__ blin,
    const _Float16* __restrict__ WT,
    _Float16* __restrict__ h2r, _Float16* __restrict__ h3r,
    int* __restrict__ flags,
    float* __restrict__ out) {
  __shared__ __align__(16) _Float16 xh1[2][16][96];   // role 0: [h1|x|pad]
  __shared__ __align__(16) _Float16 xh2[2][16][192];  // role 0: [h1|h2]
  __shared__ float wlin[2][448];                      // role 0

  const int fut = *future_p;
  const int nsteps = T_SEQ - 1 + fut;   // 271

  const int rep = blockIdx.x % NREP;
  const int role = blockIdx.x / NREP;   // 0 = front, 1..4 = L3 slices

  int* fb = flags + rep * 512;          // fl3[s] at fb+s*64, flf at fb+4*64
  const int NEG = (int)0x80000000;

  const int tid = threadIdx.x;
  const int w = tid >> 6, lane = tid & 63;
  const int n = lane & 15, l4 = lane >> 4;

  _Float16* h2b = h2r + (size_t)rep * H2_REP;
  _Float16* h3b = h3r + (size_t)rep * H3_REP;

  if (role == 0) {
    // =================== front: L1 + L2 + LIN ===================
    for (int i = tid; i < 2*16*96;  i += 256) (&xh1[0][0][0])[i] = (_Float16)0.f;
    for (int i = tid; i < 2*16*192; i += 256) (&xh2[0][0][0])[i] = (_Float16)0.f;
    for (int i = tid; i < 896; i += 256) (&wlin[0][0])[i] = Wlin[i];

    half8 a1[4][3];
#pragma unroll
    for (int q = 0; q < 4; ++q)
#pragma unroll
      for (int kk = 0; kk < 3; ++kk)
        a1[q][kk] = *(const half8*)(WT + ((q*NJT1 + w)*NKB1 + kk)*512 + lane*8);
    half8 a2[2][4][6];
#pragma unroll
    for (int u = 0; u < 2; ++u)
#pragma unroll
      for (int q = 0; q < 4; ++q)
#pragma unroll
        for (int kk = 0; kk < 6; ++kk)
          a2[u][q][kk] = *(const half8*)(WT + WSZ1 + ((q*NJT2 + (u*4+w))*NKB2 + kk)*512 + lane*8);
    float b1[4][4], b2[2][4][4];
#pragma unroll
    for (int q = 0; q < 4; ++q)
#pragma unroll
      for (int e = 0; e < 4; ++e) {
        const int r1 = q*64 + w*16 + l4*4 + e;
        b1[q][e] = bih1[r1] + bhh1[r1];
#pragma unroll
        for (int u = 0; u < 2; ++u) {
          const int r2 = q*128 + (u*4+w)*16 + l4*4 + e;
          b2[u][q][e] = bih2[r2] + bhh2[r2];
        }
      }
    float c1[2][4] = {}, c2[2][2][4] = {};
    __syncthreads();

    for (int it = 0; it <= nsteps; ++it) {
      const int tp = it - 1;
      const int tg3 = (it >= T_SEQ) ? it : it - 6;  // LIN needs fl3>=it; else backpressure
      wait_rep(fb, tg3, NEG);

      // ---- LIN(tp) -> out + x(it) ----
      if (tp >= T_SEQ - 1 && tid < 128) {
        const int kq = tid & 1, ch = (tid >> 1) & 1, nn = (tid >> 2) & 15, gl = (tid >> 6) & 1;
        const _Float16* h3p = h3b + (size_t)(tp & DMASK)*H3_SLOT + gl*H3_G + nn*256;
        float acc = 0.f;
        for (int k = kq*224; k < kq*224 + 224; k += 4) {
          half4 xv;
          if (k < 192) xv = *(const half4*)(&xh2[gl][nn][k]);
          else         { H4u u; u.u = ld64(h3p + (k - 192)); xv = u.h; }
          const float* wl = &wlin[ch][k];
          acc = fmaf(wl[0], (float)xv[0], acc);
          acc = fmaf(wl[1], (float)xv[1], acc);
          acc = fmaf(wl[2], (float)xv[2], acc);
          acc = fmaf(wl[3], (float)xv[3], acc);
        }
        acc += __shfl_xor(acc, 1, 64);
        if (kq == 0) {
          const float o = acc + blin[ch];
          out[((size_t)(rep*32 + gl*16 + nn)*fut + (tp - (T_SEQ - 1)))*2 + ch] = o;
          xh1[gl][nn][64 + ch] = (_Float16)o;
        }
      }
      if (it < T_SEQ && tid < 64) {
        const int gl = tid >> 5, nn = (tid >> 1) & 15, ch = tid & 1;
        xh1[gl][nn][64 + ch] =
            (_Float16)input[((size_t)(rep*32 + gl*16 + nn)*T_SEQ + it)*2 + ch];
      }
      __syncthreads();
      if (it == nsteps) break;

      // ---- L1(it) ----
      half8 bf1[2][3];
#pragma unroll
      for (int g = 0; g < 2; ++g)
#pragma unroll
        for (int kk = 0; kk < 3; ++kk)
          bf1[g][kk] = *(const half8*)(&xh1[g][n][kk*32 + l4*8]);
      __syncthreads();
#pragma unroll
      for (int g = 0; g < 2; ++g) {
        f32x4 acc[4];
#pragma unroll
        for (int q = 0; q < 4; ++q)
#pragma unroll
          for (int e = 0; e < 4; ++e) acc[q][e] = b1[q][e];
#pragma unroll
        for (int q = 0; q < 4; ++q)
#pragma unroll
          for (int kk = 0; kk < 3; ++kk)
            acc[q] = __builtin_amdgcn_mfma_f32_16x16x32_f16(a1[q][kk], bf1[g][kk], acc[q], 0, 0, 0);
        half4 hv;
#pragma unroll
        for (int e = 0; e < 4; ++e) {
          const float cn = sigm(acc[1][e]) * c1[g][e] + sigm(acc[0][e]) * tanh_fast(acc[2][e]);
          const float h = sigm(acc[3][e]) * tanh_fast(cn);
          c1[g][e] = cn;
          hv[e] = (_Float16)h;
        }
        *(half4*)(&xh1[g][n][w*16 + l4*4]) = hv;
        *(half4*)(&xh2[g][n][w*16 + l4*4]) = hv;
      }
      __syncthreads();

      // ---- L2(it) ----
      half8 bf2[2][6];
#pragma unroll
      for (int g = 0; g < 2; ++g)
#pragma unroll
        for (int kk = 0; kk < 6; ++kk)
          bf2[g][kk] = *(const half8*)(&xh2[g][n][kk*32 + l4*8]);
      __syncthreads();
      const int slot = it & DMASK;
#pragma unroll
      for (int u = 0; u < 2; ++u)
#pragma unroll
        for (int g = 0; g < 2; ++g) {
          f32x4 acc[4];
#pragma unroll
          for (int q = 0; q < 4; ++q)
#pragma unroll
            for (int e = 0; e < 4; ++e) acc[q][e] = b2[u][q][e];
#pragma unroll
          for (int q = 0; q < 4; ++q)
#pragma unroll
            for (int kk = 0; kk < 6; ++kk)
              acc[q] = __builtin_amdgcn_mfma_f32_16x16x32_f16(a2[u][q][kk], bf2[g][kk], acc[q], 0, 0, 0);
          half4 hv;
#pragma unroll
          for (int e = 0; e < 4; ++e) {
            const float cn = sigm(acc[1][e]) * c2[u][g][e] + sigm(acc[0][e]) * tanh_fast(acc[2][e]);
            const float h = sigm(acc[3][e]) * tanh_fast(cn);
            c2[u][g][e] = cn;
            hv[e] = (_Float16)h;
          }
          const int row = (u*4 + w)*16 + l4*4;
          *(half4*)(&xh2[g][n][64 + row]) = hv;
          st64(h2b + (size_t)slot*H2_SLOT + g*H2_G + n*128 + row, hv);
        }
      asm volatile("s_waitcnt vmcnt(0)" ::: "memory");
      __syncthreads();
      if (tid == 0) stflag(fb + 4*64, it + 1);
    }
  } else {
    // =================== L3 quarter-slice ===================
    const int slice = role - 1;          // 0..3
    const int tl = slice*4 + w;          // tile 0..15
    half8 a3[4][12];
#pragma unroll
    for (int q = 0; q < 4; ++q)
#pragma unroll
      for (int kk = 0; kk < 12; ++kk)
        a3[q][kk] = *(const half8*)(WT + WSZ1 + WSZ2 + ((q*NJT3 + tl)*NKB3 + kk)*512 + lane*8);
    float b3[4][4];
#pragma unroll
    for (int q = 0; q < 4; ++q)
#pragma unroll
      for (int e = 0; e < 4; ++e) {
        const int r = q*256 + tl*16 + l4*4 + e;
        b3[q][e] = bih3[r] + bhh3[r];
      }
    float c3[2][4] = {};

    for (int t = 0; t < nsteps; ++t) {
      wait_rep(fb, t, t + 1);            // fl3 >= t (h3(t-1)), flf >= t+1 (h2(t))
      const int slot = t & DMASK, slot1 = (t - 1) & DMASK;
      half8 bf[2][12];
#pragma unroll
      for (int g = 0; g < 2; ++g) {
        const _Float16* h2p = h2b + (size_t)slot*H2_SLOT + g*H2_G + n*128;
#pragma unroll
        for (int kk = 0; kk < 4; ++kk) bf[g][kk] = ldh8(h2p + kk*32 + l4*8);
        if (t > 0) {
          const _Float16* h3p = h3b + (size_t)slot1*H3_SLOT + g*H3_G + n*256;
#pragma unroll
          for (int kk = 4; kk < 12; ++kk) bf[g][kk] = ldh8(h3p + (kk-4)*32 + l4*8);
        } else {
#pragma unroll
          for (int kk = 4; kk < 12; ++kk) bf[g][kk] = half8{};
        }
      }
#pragma unroll
      for (int g = 0; g < 2; ++g) {
        f32x4 acc[4];
#pragma unroll
        for (int q = 0; q < 4; ++q)
#pragma unroll
          for (int e = 0; e < 4; ++e) acc[q][e] = b3[q][e];
#pragma unroll
        for (int q = 0; q < 4; ++q)
#pragma unroll
          for (int kk = 0; kk < 12; ++kk)
            acc[q] = __builtin_amdgcn_mfma_f32_16x16x32_f16(a3[q][kk], bf[g][kk], acc[q], 0, 0, 0);
        half4 hv;
#pragma unroll
        for (int e = 0; e < 4; ++e) {
          const float cn = sigm(acc[1][e]) * c3[g][e] + sigm(acc[0][e]) * tanh_fast(acc[2][e]);
          const float h = sigm(acc[3][e]) * tanh_fast(cn);
          c3[g][e] = cn;
          hv[e] = (_Float16)h;
        }
        st64(h3b + (size_t)slot*H3_SLOT + g*H3_G + n*256 + tl*16 + l4*4, hv);
      }
      asm volatile("s_waitcnt vmcnt(0)" ::: "memory");
      __syncthreads();
      if (tid == 0) stflag(fb + slice*64, t + 1);
    }
  }
}

extern "C" void kernel_launch(void* const* d_in, const int* in_sizes, int n_in,
                              void* d_out, int out_size, void* d_ws, size_t ws_size,
                              hipStream_t stream) {
  const float* input = (const float*)d_in[0];
  const int*   fut   = (const int*)d_in[1];
  const float* Wih1  = (const float*)d_in[2];
  const float* Whh1  = (const float*)d_in[3];
  const float* bih1  = (const float*)d_in[4];
  const float* bhh1  = (const float*)d_in[5];
  const float* Wih2  = (const float*)d_in[6];
  const float* Whh2  = (const float*)d_in[7];
  const float* bih2  = (const float*)d_in[8];
  const float* bhh2  = (const float*)d_in[9];
  const float* Wih3  = (const float*)d_in[10];
  const float* Whh3  = (const float*)d_in[11];
  const float* bih3  = (const float*)d_in[12];
  const float* bhh3  = (const float*)d_in[13];
  const float* Wlin  = (const float*)d_in[14];
  const float* blin  = (const float*)d_in[15];
  float* out = (float*)d_out;

  _Float16* WT  = (_Float16*)d_ws;
  _Float16* h2r = WT + WTOT;
  _Float16* h3r = h2r + (size_t)NREP * H2_REP;
  int* flags    = (int*)(h3r + (size_t)NREP * H3_REP);
  const size_t flag_bytes = (size_t)NREP * 512 * sizeof(int);  // 64 KB

  prep_weights<<<(WTOT + 255) / 256, 256, 0, stream>>>(Wih1, Whh1, Wih2, Whh2, Wih3, Whh3, WT);
  hipMemsetAsync(flags, 0, flag_bytes, stream);
  pipe_main<<<5 * NREP, 256, 0, stream>>>(input, fut,
                                          bih1, bhh1, bih2, bhh2, bih3, bhh3,
                                          Wlin, blin, WT, h2r, h3r, flags, out);
}